// Round 4
// baseline (210.724 us; speedup 1.0000x reference)
//
#include <hip/hip_runtime.h>

#define HID 64
#define NPB 256    // nodes per bucket (bucket = dst >> 8)
#define CAP 3072   // fixed per-bucket edge capacity: mean 2560, sd ~50 -> 10 sigma margin
#define DFT 512    // degfill/bucket1 block size (8 waves)
#define RCAP 6     // register-cache records per thread; RCAP*DFT=3072 >= CAP-4 covers whole bucket

typedef __attribute__((ext_vector_type(8))) short bf16x8;
typedef __attribute__((ext_vector_type(4))) float f32x4;

__device__ inline float bf2f(unsigned short u) {
  return __uint_as_float((unsigned int)u << 16);
}
__device__ inline unsigned short f2bf(float f) {
  unsigned int u = __float_as_uint(f);
  u += 0x7fff + ((u >> 16) & 1);  // round-to-nearest-even
  return (unsigned short)(u >> 16);
}
__device__ inline float bfLo(unsigned int u) { return __uint_as_float(u << 16); }
__device__ inline float bfHi(unsigned int u) { return __uint_as_float(u & 0xffff0000u); }

// ---- S1 FUSED (hist+reserve+scatter): LDS hist -> one global atomicAdd per
// bucket per block (reserve) -> scatter into fixed-capacity bucket regions.
// Bucket c occupies edges[c*CAP .. c*CAP+cnt_c). ----
__global__ __launch_bounds__(DFT) void k_bucket1(const int* __restrict__ src,
                                                 const int* __restrict__ dst,
                                                 const float* __restrict__ ew,
                                                 unsigned int* __restrict__ bucketCnt,  // B*16 padded
                                                 int2* __restrict__ edges,
                                                 int B, int ept, int nE) {
  __shared__ unsigned int hist[512];
  hist[threadIdx.x] = 0;
  __syncthreads();
  int base = blockIdx.x * DFT * ept;
  for (int i = 0; i < ept; ++i) {
    int e = base + i * DFT + threadIdx.x;
    if (e < nE) atomicAdd(&hist[(unsigned)dst[e] >> 8], 1u);
  }
  __syncthreads();
  for (int c = threadIdx.x; c < B; c += DFT) {
    unsigned int h = hist[c];
    unsigned int b = 0;
    if (h) b = atomicAdd(&bucketCnt[c * 16], h);  // 64B-padded line per bucket
    hist[c] = (unsigned)(c * CAP) + b;            // absolute write cursor
  }
  __syncthreads();
  for (int i = 0; i < ept; ++i) {
    int e = base + i * DFT + threadIdx.x;
    if (e < nE) {
      int d = dst[e];
      int c = (unsigned)d >> 8;
      int slot = (int)atomicAdd(&hist[c], 1u);
      if (slot < (c + 1) * CAP)  // never taken statistically; memory safety only
        edges[slot] = make_int2(src[e] | ((d & 255) << 24), __float_as_int(ew[e]));
    }
  }
}

// ---- S2 FUSED (degfill + degree-binning + gemm1): phase A = deg + count +
// scan + IN-PLACE row-sorted rewrite (register-cached, all reads before any
// write); builds perm[] = per-bucket degree-class counting sort so the
// aggregator's 8-node waves carry equal-degree nodes (kills max-of-8 wave
// divergence); phase B = MFMA gemm over this bucket's 256 rows with dinv in LDS.
// rowStart[g+1] = END offset of row g; starts are c*CAP arithmetically. ----
__global__ __launch_bounds__(DFT) void k_degfillG(int2* __restrict__ edges,
                                                  const unsigned int* __restrict__ bucketCnt,
                                                  const float* __restrict__ X,
                                                  const float* __restrict__ W,
                                                  float* __restrict__ dinv,
                                                  int* __restrict__ rowStart,
                                                  int* __restrict__ perm,
                                                  unsigned short* __restrict__ Out, int n) {
  __shared__ float deg[NPB];
  __shared__ int cnt[NPB];
  __shared__ int s[NPB];
  __shared__ int chist[16], cbase[16];
  if (threadIdx.x < NPB) {
    deg[threadIdx.x] = 1.0f;  // self-loop weight
    cnt[threadIdx.x] = 0;
  }
  if (threadIdx.x < 16) chist[threadIdx.x] = 0;
  __syncthreads();
  int c = blockIdx.x;
  int i0 = c * CAP;
  int bc = (int)bucketCnt[c * 16];
  if (bc > CAP - 4) bc = CAP - 4;  // never taken; memory safety
  int i1 = i0 + bc;
  int2 rec[RCAP];
  int myCnt = 0;
  for (int i = i0 + threadIdx.x; i < i1; i += DFT) {
    int2 r = edges[i];
#pragma unroll
    for (int k = 0; k < RCAP; ++k)
      if (k == myCnt) rec[k] = r;
    myCnt++;
    int l = (unsigned)r.x >> 24;
    atomicAdd(&deg[l], __int_as_float(r.y));
    atomicAdd(&cnt[l], 1);
  }
  __syncthreads();  // ALL reads of edges[] done before any write below
  int v = 0;
  if (threadIdx.x < NPB) {
    v = cnt[threadIdx.x];
    s[threadIdx.x] = v;
  }
  __syncthreads();
  for (int o = 1; o < NPB; o <<= 1) {
    int t = (threadIdx.x < NPB && threadIdx.x >= (unsigned)o) ? s[threadIdx.x - o] : 0;
    __syncthreads();
    if (threadIdx.x < NPB) s[threadIdx.x] += t;
    __syncthreads();
  }
  int g = c * NPB + threadIdx.x;
  int cls = 0, myrank = 0;
  if (threadIdx.x < NPB) {
    int rowBase = i0 + s[threadIdx.x] - v;
    float di = rsqrtf(deg[threadIdx.x]);
    if (g < n) {
      rowStart[g + 1] = i0 + s[threadIdx.x];  // inclusive end of row g
      dinv[g] = di;
      cls = v >> 1;
      if (cls > 15) cls = 15;
      myrank = atomicAdd(&chist[cls], 1);  // rank within degree class
    }
    cnt[threadIdx.x] = rowBase;  // reuse as cursor (deg reused as ddst below)
  }
  if (threadIdx.x < 4) edges[i1 + threadIdx.x] = make_int2(0, 0);  // zero sentinels
  __syncthreads();
  if (threadIdx.x == 0) {  // exclusive scan of 16 class counts
    int acc = 0;
#pragma unroll
    for (int i = 0; i < 16; ++i) { cbase[i] = acc; acc += chist[i]; }
  }
  if (threadIdx.x < NPB) deg[threadIdx.x] = rsqrtf(deg[threadIdx.x]);  // ddst = di
  __syncthreads();
  if (threadIdx.x < NPB && g < n)
    perm[c * NPB + cbase[cls] + myrank] = g;  // ranks dense from bucket base
#pragma unroll
  for (int k = 0; k < RCAP; ++k) {
    if (k < myCnt) {
      int2 r = rec[k];
      int l = (unsigned)r.x >> 24;
      int pos = atomicAdd(&cnt[l], 1);
      float norm = __int_as_float(r.y) * deg[l];  // ew * dinv[dst]
      edges[pos] = make_int2(r.x & 0xFFFFFF, __float_as_int(norm));
    }
  }
  // ---- phase B: gemm1 for rows [c*256, c*256+256). deg[] holds di. ----
  __syncthreads();
  int wv = threadIdx.x >> 6;
  int lane = threadIdx.x & 63;
  int m16 = lane & 15;
  int q = lane >> 4;
  bf16x8 Bb[4][2], Br[4][2];
#pragma unroll
  for (int nt = 0; nt < 4; ++nt)
#pragma unroll
    for (int kh = 0; kh < 2; ++kh) {
      int ncol = nt * 16 + m16;
      int k0 = kh * 32 + q * 8;
#pragma unroll
      for (int j = 0; j < 8; ++j) {
        float w = W[(k0 + j) * HID + ncol];
        unsigned short wb = f2bf(w);
        Bb[nt][kh][j] = (short)wb;
        Br[nt][kh][j] = (short)f2bf(w - bf2f(wb));
      }
    }
#pragma unroll
  for (int sub = 0; sub < 2; ++sub) {
    int slice = sub * 8 + wv;  // 16 slices of 16 rows over 8 waves x 2 iters
    int rowBase2 = c * 256 + slice * 16;
    if (rowBase2 >= n) continue;
    int mc = rowBase2 + m16;
    if (mc >= n) mc = n - 1;
    bf16x8 A[2];
    const float* Xp = X + (size_t)mc * HID;
#pragma unroll
    for (int kh = 0; kh < 2; ++kh) {
      f32x4 x0 = *(const f32x4*)(Xp + kh * 32 + q * 8);
      f32x4 x1 = *(const f32x4*)(Xp + kh * 32 + q * 8 + 4);
#pragma unroll
      for (int j = 0; j < 4; ++j) {
        A[kh][j] = (short)f2bf(x0[j]);
        A[kh][4 + j] = (short)f2bf(x1[j]);
      }
    }
    float dv = deg[slice * 16 + m16];  // di for row rowBase2+m16 (LDS)
#pragma unroll
    for (int nt = 0; nt < 4; ++nt) {
      f32x4 acc = {0.f, 0.f, 0.f, 0.f};
      // swapped operands -> D transposed: lane holds row rowBase2+m16,
      // cols nt*16 + q*4 + r  => one contiguous 8B bf16x4 store per nt
      acc = __builtin_amdgcn_mfma_f32_16x16x32_bf16(Bb[nt][0], A[0], acc, 0, 0, 0);
      acc = __builtin_amdgcn_mfma_f32_16x16x32_bf16(Bb[nt][1], A[1], acc, 0, 0, 0);
      acc = __builtin_amdgcn_mfma_f32_16x16x32_bf16(Br[nt][0], A[0], acc, 0, 0, 0);
      acc = __builtin_amdgcn_mfma_f32_16x16x32_bf16(Br[nt][1], A[1], acc, 0, 0, 0);
      if (rowBase2 + m16 < n) {
        ushort4 o;
        o.x = f2bf(acc[0] * dv);
        o.y = f2bf(acc[1] * dv);
        o.z = f2bf(acc[2] * dv);
        o.w = f2bf(acc[3] * dv);
        *(ushort4*)(&Out[(size_t)(rowBase2 + m16) * HID + nt * 16 + q * 4]) = o;
      }
    }
  }
}

// ---- standalone MFMA gemm (layer 2), transposed-D stores ----
template <typename TI>
__global__ __launch_bounds__(256) void k_gemmMF(const TI* __restrict__ X,
                                                const float* __restrict__ W,
                                                const float* __restrict__ dinv,
                                                unsigned short* __restrict__ Out,
                                                int n, int nTiles) {
  int wv = threadIdx.x >> 6;
  int lane = threadIdx.x & 63;
  int m16 = lane & 15;
  int q = lane >> 4;
  bf16x8 Bb[4][2], Br[4][2];
#pragma unroll
  for (int nt = 0; nt < 4; ++nt)
#pragma unroll
    for (int kh = 0; kh < 2; ++kh) {
      int ncol = nt * 16 + m16;
      int k0 = kh * 32 + q * 8;
#pragma unroll
      for (int j = 0; j < 8; ++j) {
        float w = W[(k0 + j) * HID + ncol];
        unsigned short wb = f2bf(w);
        Bb[nt][kh][j] = (short)wb;
        Br[nt][kh][j] = (short)f2bf(w - bf2f(wb));
      }
    }
  for (int t = blockIdx.x; t < nTiles; t += gridDim.x) {
    int rowBase = t * 64 + wv * 16;
    if (rowBase >= n) continue;
    int mc = rowBase + m16;
    if (mc >= n) mc = n - 1;
    bf16x8 A[2];
    if (sizeof(TI) == 2) {
      const unsigned short* Xp = (const unsigned short*)X + (size_t)mc * HID;
      A[0] = *(const bf16x8*)(Xp + q * 8);
      A[1] = *(const bf16x8*)(Xp + 32 + q * 8);
    } else {
      const float* Xp = (const float*)X + (size_t)mc * HID;
#pragma unroll
      for (int kh = 0; kh < 2; ++kh) {
        f32x4 x0 = *(const f32x4*)(Xp + kh * 32 + q * 8);
        f32x4 x1 = *(const f32x4*)(Xp + kh * 32 + q * 8 + 4);
#pragma unroll
        for (int j = 0; j < 4; ++j) {
          A[kh][j] = (short)f2bf(x0[j]);
          A[kh][4 + j] = (short)f2bf(x1[j]);
        }
      }
    }
    float dv = dinv[mc];
#pragma unroll
    for (int nt = 0; nt < 4; ++nt) {
      f32x4 acc = {0.f, 0.f, 0.f, 0.f};
      acc = __builtin_amdgcn_mfma_f32_16x16x32_bf16(Bb[nt][0], A[0], acc, 0, 0, 0);
      acc = __builtin_amdgcn_mfma_f32_16x16x32_bf16(Bb[nt][1], A[1], acc, 0, 0, 0);
      acc = __builtin_amdgcn_mfma_f32_16x16x32_bf16(Br[nt][0], A[0], acc, 0, 0, 0);
      acc = __builtin_amdgcn_mfma_f32_16x16x32_bf16(Br[nt][1], A[1], acc, 0, 0, 0);
      if (rowBase + m16 < n) {
        ushort4 o;
        o.x = f2bf(acc[0] * dv);
        o.y = f2bf(acc[1] * dv);
        o.z = f2bf(acc[2] * dv);
        o.w = f2bf(acc[3] * dv);
        *(ushort4*)(&Out[(size_t)(rowBase + m16) * HID + nt * 16 + q * 4]) = o;
      }
    }
  }
}

// ---- CSR aggregate: 8 nodes per wave via degree-binned perm[] (equal-degree
// nodes per wave -> no max-of-8 loop divergence). 8-lane group = node, lane
// covers 8 channels via one uint4 = 128B row in ONE VMEM instr. ----
template <int OUT_BF16>
__global__ __launch_bounds__(256) void k_agg8(const int2* __restrict__ edges,
                                              const int* __restrict__ rowStart,
                                              const int* __restrict__ perm,
                                              const float* __restrict__ dinv,
                                              const uint4* __restrict__ H8,  // 8 x uint4 per node
                                              const float* __restrict__ bias,
                                              void* __restrict__ outp, int n) {
  int gwave = (blockIdx.x * 256 + threadIdx.x) >> 6;
  int lane = threadIdx.x & 63;
  int q = lane >> 3;    // which of 8 slots in this wave
  int ql = lane & 7;    // channels 8*ql .. 8*ql+7
  int slot = gwave * 8 + q;
  if (slot >= n) return;  // perm ranks are dense from each bucket base
  int node = perm[slot];
  int e0 = rowStart[node];
  if ((node & 255) == 0) e0 = (node >> 8) * CAP;  // bucket start (rowStart[g] holds ends)
  int e1 = rowStart[node + 1];
  float di = dinv[node];
  uint4 su = H8[(size_t)node * 8 + ql];
  float a0 = di * bfLo(su.x), a1 = di * bfHi(su.x);
  float a2 = di * bfLo(su.y), a3 = di * bfHi(su.y);
  float a4 = di * bfLo(su.z), a5 = di * bfHi(su.z);
  float a6 = di * bfLo(su.w), a7 = di * bfHi(su.w);
  for (int base = e0 & ~1; base < e1; base += 4) {
    int4 p0 = *(const int4*)(edges + base);
    int4 p1 = *(const int4*)(edges + base + 2);
    uint4 h0 = H8[(size_t)(unsigned)p0.x * 8u + ql];
    uint4 h1 = H8[(size_t)(unsigned)p0.z * 8u + ql];
    uint4 h2 = H8[(size_t)(unsigned)p1.x * 8u + ql];
    uint4 h3 = H8[(size_t)(unsigned)p1.z * 8u + ql];
    float n0 = (base >= e0) ? __int_as_float(p0.y) : 0.f;
    float n1 = (base + 1 < e1) ? __int_as_float(p0.w) : 0.f;
    float n2 = (base + 2 < e1) ? __int_as_float(p1.y) : 0.f;
    float n3 = (base + 3 < e1) ? __int_as_float(p1.w) : 0.f;
    a0 = fmaf(n0, bfLo(h0.x), a0); a1 = fmaf(n0, bfHi(h0.x), a1);
    a2 = fmaf(n0, bfLo(h0.y), a2); a3 = fmaf(n0, bfHi(h0.y), a3);
    a4 = fmaf(n0, bfLo(h0.z), a4); a5 = fmaf(n0, bfHi(h0.z), a5);
    a6 = fmaf(n0, bfLo(h0.w), a6); a7 = fmaf(n0, bfHi(h0.w), a7);
    a0 = fmaf(n1, bfLo(h1.x), a0); a1 = fmaf(n1, bfHi(h1.x), a1);
    a2 = fmaf(n1, bfLo(h1.y), a2); a3 = fmaf(n1, bfHi(h1.y), a3);
    a4 = fmaf(n1, bfLo(h1.z), a4); a5 = fmaf(n1, bfHi(h1.z), a5);
    a6 = fmaf(n1, bfLo(h1.w), a6); a7 = fmaf(n1, bfHi(h1.w), a7);
    a0 = fmaf(n2, bfLo(h2.x), a0); a1 = fmaf(n2, bfHi(h2.x), a1);
    a2 = fmaf(n2, bfLo(h2.y), a2); a3 = fmaf(n2, bfHi(h2.y), a3);
    a4 = fmaf(n2, bfLo(h2.z), a4); a5 = fmaf(n2, bfHi(h2.z), a5);
    a6 = fmaf(n2, bfLo(h2.w), a6); a7 = fmaf(n2, bfHi(h2.w), a7);
    a0 = fmaf(n3, bfLo(h3.x), a0); a1 = fmaf(n3, bfHi(h3.x), a1);
    a2 = fmaf(n3, bfLo(h3.y), a2); a3 = fmaf(n3, bfHi(h3.y), a3);
    a4 = fmaf(n3, bfLo(h3.z), a4); a5 = fmaf(n3, bfHi(h3.z), a5);
    a6 = fmaf(n3, bfLo(h3.w), a6); a7 = fmaf(n3, bfHi(h3.w), a7);
  }
  float4 bv0 = ((const float4*)bias)[2 * ql];
  float4 bv1 = ((const float4*)bias)[2 * ql + 1];
  a0 += bv0.x; a1 += bv0.y; a2 += bv0.z; a3 += bv0.w;
  a4 += bv1.x; a5 += bv1.y; a6 += bv1.z; a7 += bv1.w;
  if (OUT_BF16) {
    a0 = fmaxf(a0, 0.f); a1 = fmaxf(a1, 0.f); a2 = fmaxf(a2, 0.f); a3 = fmaxf(a3, 0.f);
    a4 = fmaxf(a4, 0.f); a5 = fmaxf(a5, 0.f); a6 = fmaxf(a6, 0.f); a7 = fmaxf(a7, 0.f);
    uint4 o;
    o.x = (unsigned)f2bf(a0) | ((unsigned)f2bf(a1) << 16);
    o.y = (unsigned)f2bf(a2) | ((unsigned)f2bf(a3) << 16);
    o.z = (unsigned)f2bf(a4) | ((unsigned)f2bf(a5) << 16);
    o.w = (unsigned)f2bf(a6) | ((unsigned)f2bf(a7) << 16);
    ((uint4*)outp)[(size_t)node * 8 + ql] = o;
  } else {
    float4 o0, o1;
    o0.x = a0; o0.y = a1; o0.z = a2; o0.w = a3;
    o1.x = a4; o1.y = a5; o1.z = a6; o1.w = a7;
    ((float4*)outp)[(size_t)node * 16 + 2 * ql] = o0;
    ((float4*)outp)[(size_t)node * 16 + 2 * ql + 1] = o1;
  }
}

extern "C" void kernel_launch(void* const* d_in, const int* in_sizes, int n_in,
                              void* d_out, int out_size, void* d_ws, size_t ws_size,
                              hipStream_t stream) {
  const float* x  = (const float*)d_in[0];
  const int*   ei = (const int*)d_in[1];
  const float* ew = (const float*)d_in[2];
  const float* W1 = (const float*)d_in[3];
  const float* b1 = (const float*)d_in[4];
  const float* W2 = (const float*)d_in[5];
  const float* b2 = (const float*)d_in[6];
  float* out = (float*)d_out;

  const int n  = in_sizes[0] / HID;   // 100000
  const int nE = in_sizes[2];         // 1000000
  const int* src = ei;
  const int* dst = ei + nE;

  const int B = (n + NPB - 1) / NPB;  // 391 buckets
  const int G1  = (nE + DFT * 4 - 1) / (DFT * 4);     // 489 blocks
  const int ept = (nE + G1 * DFT - 1) / (G1 * DFT);   // 4

  // ---- workspace layout (~23.6 MB) ----
  auto align512 = [](size_t v) { return (v + 511) & ~(size_t)511; };
  char* ws = (char*)d_ws;
  size_t off = 0;
  float* dinv        = (float*)(ws + off); off += align512((size_t)n * 4);
  int*   rowStart    = (int*)  (ws + off); off += align512((size_t)(n + 1) * 4);
  int*   perm        = (int*)  (ws + off); off += align512((size_t)B * NPB * 4);
  unsigned int* bucketCnt = (unsigned int*)(ws + off); off += align512((size_t)B * 16 * 4);
  int2*  edges       = (int2*) (ws + off); off += align512((size_t)B * CAP * 8 + 64);
  unsigned short* bufA = (unsigned short*)(ws + off); off += align512((size_t)n * HID * 2);
  // bufB (12.8 MB of bf16 H) lives in d_out (25.6 MB): dead before the final
  // aggregate writes out, which fully overwrites d_out.
  unsigned short* bufB = (unsigned short*)d_out;

  const int aggBlocks = (((n + 7) / 8) * 64 + 255) / 256;  // 8 nodes per wave
  const int nTiles = (n + 63) / 64;                         // 64-row gemm tiles

  // ---- CSR build + layer-1 projection ----
  hipMemsetAsync(bucketCnt, 0, (size_t)B * 16 * 4, stream);
  k_bucket1<<<G1, DFT, 0, stream>>>(src, dst, ew, bucketCnt, edges, B, ept, nE);
  k_degfillG<<<B, DFT, 0, stream>>>(edges, bucketCnt, x, W1, dinv, rowStart, perm, bufA, n);

  // ---- layer 1 aggregate ----
  k_agg8<1><<<aggBlocks, 256, 0, stream>>>(edges, rowStart, perm, dinv,
                                           (const uint4*)bufA, b1, bufB, n);

  // ---- layer 2 ----
  k_gemmMF<unsigned short><<<1024, 256, 0, stream>>>(bufB, W2, dinv, bufA, n, nTiles);
  k_agg8<0><<<aggBlocks, 256, 0, stream>>>(edges, rowStart, perm, dinv,
                                           (const uint4*)bufA, b2, out, n);
}

// Round 5
// 182.373 us; speedup vs baseline: 1.1555x; 1.1555x over previous
//
#include <hip/hip_runtime.h>

#define HID 64
#define NPB 256    // nodes per bucket (bucket = dst >> 8)
#define CAP 3072   // fixed per-bucket edge capacity: mean 2560, sd ~50 -> 10 sigma margin
#define DFT 512    // degfill/bucket1 block size (8 waves)
#define RCAP 6     // register-cache records per thread; RCAP*DFT=3072 >= CAP-4 covers whole bucket

typedef __attribute__((ext_vector_type(8))) short bf16x8;
typedef __attribute__((ext_vector_type(4))) float f32x4;

__device__ inline float bf2f(unsigned short u) {
  return __uint_as_float((unsigned int)u << 16);
}
__device__ inline unsigned short f2bf(float f) {
  unsigned int u = __float_as_uint(f);
  u += 0x7fff + ((u >> 16) & 1);  // round-to-nearest-even
  return (unsigned short)(u >> 16);
}
__device__ inline float bfLo(unsigned int u) { return __uint_as_float(u << 16); }
__device__ inline float bfHi(unsigned int u) { return __uint_as_float(u & 0xffff0000u); }

// ---- S1 FUSED (hist+reserve+scatter): LDS hist -> one global atomicAdd per
// bucket per block (reserve) -> scatter into fixed-capacity bucket regions.
// Bucket c occupies edges[c*CAP .. c*CAP+cnt_c). ----
__global__ __launch_bounds__(DFT) void k_bucket1(const int* __restrict__ src,
                                                 const int* __restrict__ dst,
                                                 const float* __restrict__ ew,
                                                 unsigned int* __restrict__ bucketCnt,  // B*16 padded
                                                 int2* __restrict__ edges,
                                                 int B, int ept, int nE) {
  __shared__ unsigned int hist[512];
  hist[threadIdx.x] = 0;
  __syncthreads();
  int base = blockIdx.x * DFT * ept;
  for (int i = 0; i < ept; ++i) {
    int e = base + i * DFT + threadIdx.x;
    if (e < nE) atomicAdd(&hist[(unsigned)dst[e] >> 8], 1u);
  }
  __syncthreads();
  for (int c = threadIdx.x; c < B; c += DFT) {
    unsigned int h = hist[c];
    unsigned int b = 0;
    if (h) b = atomicAdd(&bucketCnt[c * 16], h);  // 64B-padded line per bucket
    hist[c] = (unsigned)(c * CAP) + b;            // absolute write cursor
  }
  __syncthreads();
  for (int i = 0; i < ept; ++i) {
    int e = base + i * DFT + threadIdx.x;
    if (e < nE) {
      int d = dst[e];
      int c = (unsigned)d >> 8;
      int slot = (int)atomicAdd(&hist[c], 1u);
      if (slot < (c + 1) * CAP)  // never taken statistically; memory safety only
        edges[slot] = make_int2(src[e] | ((d & 255) << 24), __float_as_int(ew[e]));
    }
  }
}

// ---- S2 FUSED (degfill + gemm1): phase A = deg + count + scan + IN-PLACE
// row-sorted rewrite (register-cached, all reads before any write); phase B =
// MFMA gemm over this bucket's 256 rows with dinv in LDS. Out = P1 lives in
// d_out's first half (dead before the final aggregate overwrites d_out).
// rowStart[g+1] = END offset of row g; starts are c*CAP arithmetically. ----
__global__ __launch_bounds__(DFT) void k_degfillG(int2* __restrict__ edges,
                                                  const unsigned int* __restrict__ bucketCnt,
                                                  const float* __restrict__ X,
                                                  const float* __restrict__ W,
                                                  float* __restrict__ dinv,
                                                  int* __restrict__ rowStart,
                                                  unsigned short* __restrict__ Out, int n) {
  __shared__ float deg[NPB];
  __shared__ int cnt[NPB];
  __shared__ int s[NPB];
  if (threadIdx.x < NPB) {
    deg[threadIdx.x] = 1.0f;  // self-loop weight
    cnt[threadIdx.x] = 0;
  }
  __syncthreads();
  int c = blockIdx.x;
  int i0 = c * CAP;
  int bc = (int)bucketCnt[c * 16];
  if (bc > CAP - 4) bc = CAP - 4;  // never taken; memory safety
  int i1 = i0 + bc;
  int2 rec[RCAP];
  int myCnt = 0;
  for (int i = i0 + threadIdx.x; i < i1; i += DFT) {
    int2 r = edges[i];
#pragma unroll
    for (int k = 0; k < RCAP; ++k)
      if (k == myCnt) rec[k] = r;
    myCnt++;
    int l = (unsigned)r.x >> 24;
    atomicAdd(&deg[l], __int_as_float(r.y));
    atomicAdd(&cnt[l], 1);
  }
  __syncthreads();  // ALL reads of edges[] done before any write below
  int v = 0;
  if (threadIdx.x < NPB) {
    v = cnt[threadIdx.x];
    s[threadIdx.x] = v;
  }
  __syncthreads();
  for (int o = 1; o < NPB; o <<= 1) {
    int t = (threadIdx.x < NPB && threadIdx.x >= (unsigned)o) ? s[threadIdx.x - o] : 0;
    __syncthreads();
    if (threadIdx.x < NPB) s[threadIdx.x] += t;
    __syncthreads();
  }
  if (threadIdx.x < NPB) {
    int rowBase = i0 + s[threadIdx.x] - v;
    float di = rsqrtf(deg[threadIdx.x]);
    int g = c * NPB + threadIdx.x;
    if (g < n) {
      rowStart[g + 1] = i0 + s[threadIdx.x];  // inclusive end of row g
      dinv[g] = di;
    }
    cnt[threadIdx.x] = rowBase;  // reuse as cursor (deg reused as ddst below)
  }
  if (threadIdx.x < 4) edges[i1 + threadIdx.x] = make_int2(0, 0);  // zero sentinels
  __syncthreads();
  if (threadIdx.x < NPB) deg[threadIdx.x] = rsqrtf(deg[threadIdx.x]);  // ddst = di
  __syncthreads();
#pragma unroll
  for (int k = 0; k < RCAP; ++k) {
    if (k < myCnt) {
      int2 r = rec[k];
      int l = (unsigned)r.x >> 24;
      int pos = atomicAdd(&cnt[l], 1);
      float norm = __int_as_float(r.y) * deg[l];  // ew * dinv[dst]
      edges[pos] = make_int2(r.x & 0xFFFFFF, __float_as_int(norm));
    }
  }
  // ---- phase B: gemm1 for rows [c*256, c*256+256). deg[] holds di. ----
  __syncthreads();
  int wv = threadIdx.x >> 6;
  int lane = threadIdx.x & 63;
  int m16 = lane & 15;
  int q = lane >> 4;
  bf16x8 Bb[4][2], Br[4][2];
#pragma unroll
  for (int nt = 0; nt < 4; ++nt)
#pragma unroll
    for (int kh = 0; kh < 2; ++kh) {
      int ncol = nt * 16 + m16;
      int k0 = kh * 32 + q * 8;
#pragma unroll
      for (int j = 0; j < 8; ++j) {
        float w = W[(k0 + j) * HID + ncol];
        unsigned short wb = f2bf(w);
        Bb[nt][kh][j] = (short)wb;
        Br[nt][kh][j] = (short)f2bf(w - bf2f(wb));
      }
    }
#pragma unroll
  for (int sub = 0; sub < 2; ++sub) {
    int slice = sub * 8 + wv;  // 16 slices of 16 rows over 8 waves x 2 iters
    int rowBase2 = c * 256 + slice * 16;
    if (rowBase2 >= n) continue;
    int mc = rowBase2 + m16;
    if (mc >= n) mc = n - 1;
    bf16x8 A[2];
    const float* Xp = X + (size_t)mc * HID;
#pragma unroll
    for (int kh = 0; kh < 2; ++kh) {
      f32x4 x0 = *(const f32x4*)(Xp + kh * 32 + q * 8);
      f32x4 x1 = *(const f32x4*)(Xp + kh * 32 + q * 8 + 4);
#pragma unroll
      for (int j = 0; j < 4; ++j) {
        A[kh][j] = (short)f2bf(x0[j]);
        A[kh][4 + j] = (short)f2bf(x1[j]);
      }
    }
    float dv = deg[slice * 16 + m16];  // di for row rowBase2+m16 (LDS)
#pragma unroll
    for (int nt = 0; nt < 4; ++nt) {
      f32x4 acc = {0.f, 0.f, 0.f, 0.f};
      // swapped operands -> D transposed: lane holds row rowBase2+m16,
      // cols nt*16 + q*4 + r  => one contiguous 8B bf16x4 store per nt
      acc = __builtin_amdgcn_mfma_f32_16x16x32_bf16(Bb[nt][0], A[0], acc, 0, 0, 0);
      acc = __builtin_amdgcn_mfma_f32_16x16x32_bf16(Bb[nt][1], A[1], acc, 0, 0, 0);
      acc = __builtin_amdgcn_mfma_f32_16x16x32_bf16(Br[nt][0], A[0], acc, 0, 0, 0);
      acc = __builtin_amdgcn_mfma_f32_16x16x32_bf16(Br[nt][1], A[1], acc, 0, 0, 0);
      if (rowBase2 + m16 < n) {
        ushort4 o;
        o.x = f2bf(acc[0] * dv);
        o.y = f2bf(acc[1] * dv);
        o.z = f2bf(acc[2] * dv);
        o.w = f2bf(acc[3] * dv);
        *(ushort4*)(&Out[(size_t)(rowBase2 + m16) * HID + nt * 16 + q * 4]) = o;
      }
    }
  }
}

// ---- FUSED layer-1 aggregate + layer-2 projection: each block owns 32 nodes
// (4 waves x 8). Wave computes ReLU(agg+b1) rows -> 5KB LDS -> each wave runs
// one 16-col n-tile of the 32-row MFMA gemm (W2 frags, transposed-D stores).
// Writes P2 = bf16(dinv*(h1@W2)) to workspace; never touches d_out (P1 src). ----
__global__ __launch_bounds__(256) void k_aggG(const int2* __restrict__ edges,
                                              const int* __restrict__ rowStart,
                                              const float* __restrict__ dinv,
                                              const uint4* __restrict__ H8,  // P1: 8 x uint4 per node
                                              const float* __restrict__ bias,
                                              const float* __restrict__ W,   // W2
                                              unsigned short* __restrict__ Out,  // P2
                                              int n) {
  __shared__ uint4 sh[32][10];  // [row][uint4 col], padded 8->10
  __shared__ float sdi[32];
  int wv = threadIdx.x >> 6;
  int lane = threadIdx.x & 63;
  int q = lane >> 3;    // which of 8 nodes in this wave
  int ql = lane & 7;    // channels 8*ql .. 8*ql+7
  int base = blockIdx.x * 32;
  int node = base + wv * 8 + q;
  if (node < n) {
    int e0 = rowStart[node];
    if ((node & 255) == 0) e0 = (node >> 8) * CAP;  // bucket start (rowStart[g] holds ends)
    int e1 = rowStart[node + 1];
    float di = dinv[node];
    uint4 su = H8[(size_t)node * 8 + ql];
    float a0 = di * bfLo(su.x), a1 = di * bfHi(su.x);
    float a2 = di * bfLo(su.y), a3 = di * bfHi(su.y);
    float a4 = di * bfLo(su.z), a5 = di * bfHi(su.z);
    float a6 = di * bfLo(su.w), a7 = di * bfHi(su.w);
    for (int b2 = e0 & ~1; b2 < e1; b2 += 4) {
      int4 p0 = *(const int4*)(edges + b2);
      int4 p1 = *(const int4*)(edges + b2 + 2);
      uint4 h0 = H8[(size_t)(unsigned)p0.x * 8u + ql];
      uint4 h1 = H8[(size_t)(unsigned)p0.z * 8u + ql];
      uint4 h2 = H8[(size_t)(unsigned)p1.x * 8u + ql];
      uint4 h3 = H8[(size_t)(unsigned)p1.z * 8u + ql];
      float n0 = (b2 >= e0) ? __int_as_float(p0.y) : 0.f;
      float n1 = (b2 + 1 < e1) ? __int_as_float(p0.w) : 0.f;
      float n2 = (b2 + 2 < e1) ? __int_as_float(p1.y) : 0.f;
      float n3 = (b2 + 3 < e1) ? __int_as_float(p1.w) : 0.f;
      a0 = fmaf(n0, bfLo(h0.x), a0); a1 = fmaf(n0, bfHi(h0.x), a1);
      a2 = fmaf(n0, bfLo(h0.y), a2); a3 = fmaf(n0, bfHi(h0.y), a3);
      a4 = fmaf(n0, bfLo(h0.z), a4); a5 = fmaf(n0, bfHi(h0.z), a5);
      a6 = fmaf(n0, bfLo(h0.w), a6); a7 = fmaf(n0, bfHi(h0.w), a7);
      a0 = fmaf(n1, bfLo(h1.x), a0); a1 = fmaf(n1, bfHi(h1.x), a1);
      a2 = fmaf(n1, bfLo(h1.y), a2); a3 = fmaf(n1, bfHi(h1.y), a3);
      a4 = fmaf(n1, bfLo(h1.z), a4); a5 = fmaf(n1, bfHi(h1.z), a5);
      a6 = fmaf(n1, bfLo(h1.w), a6); a7 = fmaf(n1, bfHi(h1.w), a7);
      a0 = fmaf(n2, bfLo(h2.x), a0); a1 = fmaf(n2, bfHi(h2.x), a1);
      a2 = fmaf(n2, bfLo(h2.y), a2); a3 = fmaf(n2, bfHi(h2.y), a3);
      a4 = fmaf(n2, bfLo(h2.z), a4); a5 = fmaf(n2, bfHi(h2.z), a5);
      a6 = fmaf(n2, bfLo(h2.w), a6); a7 = fmaf(n2, bfHi(h2.w), a7);
      a0 = fmaf(n3, bfLo(h3.x), a0); a1 = fmaf(n3, bfHi(h3.x), a1);
      a2 = fmaf(n3, bfLo(h3.y), a2); a3 = fmaf(n3, bfHi(h3.y), a3);
      a4 = fmaf(n3, bfLo(h3.z), a4); a5 = fmaf(n3, bfHi(h3.z), a5);
      a6 = fmaf(n3, bfLo(h3.w), a6); a7 = fmaf(n3, bfHi(h3.w), a7);
    }
    float4 bv0 = ((const float4*)bias)[2 * ql];
    float4 bv1 = ((const float4*)bias)[2 * ql + 1];
    a0 = fmaxf(a0 + bv0.x, 0.f); a1 = fmaxf(a1 + bv0.y, 0.f);
    a2 = fmaxf(a2 + bv0.z, 0.f); a3 = fmaxf(a3 + bv0.w, 0.f);
    a4 = fmaxf(a4 + bv1.x, 0.f); a5 = fmaxf(a5 + bv1.y, 0.f);
    a6 = fmaxf(a6 + bv1.z, 0.f); a7 = fmaxf(a7 + bv1.w, 0.f);
    uint4 o;
    o.x = (unsigned)f2bf(a0) | ((unsigned)f2bf(a1) << 16);
    o.y = (unsigned)f2bf(a2) | ((unsigned)f2bf(a3) << 16);
    o.z = (unsigned)f2bf(a4) | ((unsigned)f2bf(a5) << 16);
    o.w = (unsigned)f2bf(a6) | ((unsigned)f2bf(a7) << 16);
    sh[wv * 8 + q][ql] = o;
    if (ql == 0) sdi[wv * 8 + q] = di;
  } else {
    sh[wv * 8 + q][ql] = make_uint4(0, 0, 0, 0);
    if (ql == 0) sdi[wv * 8 + q] = 0.f;
  }
  __syncthreads();
  // ---- gemm2 phase: 32 rows from LDS; this wave owns n-tile nt = wv ----
  int m16 = lane & 15;
  int qq = lane >> 4;
  bf16x8 Bb[2], Br[2];
#pragma unroll
  for (int kh = 0; kh < 2; ++kh) {
    int ncol = wv * 16 + m16;
    int k0 = kh * 32 + qq * 8;
#pragma unroll
    for (int j = 0; j < 8; ++j) {
      float w = W[(k0 + j) * HID + ncol];  // L1-hot (16 KB)
      unsigned short wb = f2bf(w);
      Bb[kh][j] = (short)wb;
      Br[kh][j] = (short)f2bf(w - bf2f(wb));
    }
  }
#pragma unroll
  for (int rt = 0; rt < 2; ++rt) {
    int row = rt * 16 + m16;
    bf16x8 A0 = *(const bf16x8*)&sh[row][qq];      // k = qq*8 .. +7
    bf16x8 A1 = *(const bf16x8*)&sh[row][4 + qq];  // k = 32 + qq*8 .. +7
    f32x4 acc = {0.f, 0.f, 0.f, 0.f};
    acc = __builtin_amdgcn_mfma_f32_16x16x32_bf16(Bb[0], A0, acc, 0, 0, 0);
    acc = __builtin_amdgcn_mfma_f32_16x16x32_bf16(Bb[1], A1, acc, 0, 0, 0);
    acc = __builtin_amdgcn_mfma_f32_16x16x32_bf16(Br[0], A0, acc, 0, 0, 0);
    acc = __builtin_amdgcn_mfma_f32_16x16x32_bf16(Br[1], A1, acc, 0, 0, 0);
    int gnode = base + row;
    if (gnode < n) {
      float dv = sdi[row];
      ushort4 o;
      o.x = f2bf(acc[0] * dv);
      o.y = f2bf(acc[1] * dv);
      o.z = f2bf(acc[2] * dv);
      o.w = f2bf(acc[3] * dv);
      *(ushort4*)(&Out[(size_t)gnode * HID + wv * 16 + qq * 4]) = o;
    }
  }
}

// ---- CSR aggregate (layer 2): 8 nodes per wave, float4 output + bias ----
__global__ __launch_bounds__(256) void k_agg8f(const int2* __restrict__ edges,
                                               const int* __restrict__ rowStart,
                                               const float* __restrict__ dinv,
                                               const uint4* __restrict__ H8,  // P2
                                               const float* __restrict__ bias,
                                               float* __restrict__ outp, int n) {
  int gwave = (blockIdx.x * 256 + threadIdx.x) >> 6;
  int lane = threadIdx.x & 63;
  int q = lane >> 3;
  int ql = lane & 7;
  int node = gwave * 8 + q;
  if (node >= n) return;
  int e0 = rowStart[node];
  if ((node & 255) == 0) e0 = (node >> 8) * CAP;
  int e1 = rowStart[node + 1];
  float di = dinv[node];
  uint4 su = H8[(size_t)node * 8 + ql];
  float a0 = di * bfLo(su.x), a1 = di * bfHi(su.x);
  float a2 = di * bfLo(su.y), a3 = di * bfHi(su.y);
  float a4 = di * bfLo(su.z), a5 = di * bfHi(su.z);
  float a6 = di * bfLo(su.w), a7 = di * bfHi(su.w);
  for (int base = e0 & ~1; base < e1; base += 4) {
    int4 p0 = *(const int4*)(edges + base);
    int4 p1 = *(const int4*)(edges + base + 2);
    uint4 h0 = H8[(size_t)(unsigned)p0.x * 8u + ql];
    uint4 h1 = H8[(size_t)(unsigned)p0.z * 8u + ql];
    uint4 h2 = H8[(size_t)(unsigned)p1.x * 8u + ql];
    uint4 h3 = H8[(size_t)(unsigned)p1.z * 8u + ql];
    float n0 = (base >= e0) ? __int_as_float(p0.y) : 0.f;
    float n1 = (base + 1 < e1) ? __int_as_float(p0.w) : 0.f;
    float n2 = (base + 2 < e1) ? __int_as_float(p1.y) : 0.f;
    float n3 = (base + 3 < e1) ? __int_as_float(p1.w) : 0.f;
    a0 = fmaf(n0, bfLo(h0.x), a0); a1 = fmaf(n0, bfHi(h0.x), a1);
    a2 = fmaf(n0, bfLo(h0.y), a2); a3 = fmaf(n0, bfHi(h0.y), a3);
    a4 = fmaf(n0, bfLo(h0.z), a4); a5 = fmaf(n0, bfHi(h0.z), a5);
    a6 = fmaf(n0, bfLo(h0.w), a6); a7 = fmaf(n0, bfHi(h0.w), a7);
    a0 = fmaf(n1, bfLo(h1.x), a0); a1 = fmaf(n1, bfHi(h1.x), a1);
    a2 = fmaf(n1, bfLo(h1.y), a2); a3 = fmaf(n1, bfHi(h1.y), a3);
    a4 = fmaf(n1, bfLo(h1.z), a4); a5 = fmaf(n1, bfHi(h1.z), a5);
    a6 = fmaf(n1, bfLo(h1.w), a6); a7 = fmaf(n1, bfHi(h1.w), a7);
    a0 = fmaf(n2, bfLo(h2.x), a0); a1 = fmaf(n2, bfHi(h2.x), a1);
    a2 = fmaf(n2, bfLo(h2.y), a2); a3 = fmaf(n2, bfHi(h2.y), a3);
    a4 = fmaf(n2, bfLo(h2.z), a4); a5 = fmaf(n2, bfHi(h2.z), a5);
    a6 = fmaf(n2, bfLo(h2.w), a6); a7 = fmaf(n2, bfHi(h2.w), a7);
    a0 = fmaf(n3, bfLo(h3.x), a0); a1 = fmaf(n3, bfHi(h3.x), a1);
    a2 = fmaf(n3, bfLo(h3.y), a2); a3 = fmaf(n3, bfHi(h3.y), a3);
    a4 = fmaf(n3, bfLo(h3.z), a4); a5 = fmaf(n3, bfHi(h3.z), a5);
    a6 = fmaf(n3, bfLo(h3.w), a6); a7 = fmaf(n3, bfHi(h3.w), a7);
  }
  float4 bv0 = ((const float4*)bias)[2 * ql];
  float4 bv1 = ((const float4*)bias)[2 * ql + 1];
  float4 o0, o1;
  o0.x = a0 + bv0.x; o0.y = a1 + bv0.y; o0.z = a2 + bv0.z; o0.w = a3 + bv0.w;
  o1.x = a4 + bv1.x; o1.y = a5 + bv1.y; o1.z = a6 + bv1.z; o1.w = a7 + bv1.w;
  ((float4*)outp)[(size_t)node * 16 + 2 * ql] = o0;
  ((float4*)outp)[(size_t)node * 16 + 2 * ql + 1] = o1;
}

extern "C" void kernel_launch(void* const* d_in, const int* in_sizes, int n_in,
                              void* d_out, int out_size, void* d_ws, size_t ws_size,
                              hipStream_t stream) {
  const float* x  = (const float*)d_in[0];
  const int*   ei = (const int*)d_in[1];
  const float* ew = (const float*)d_in[2];
  const float* W1 = (const float*)d_in[3];
  const float* b1 = (const float*)d_in[4];
  const float* W2 = (const float*)d_in[5];
  const float* b2 = (const float*)d_in[6];
  float* out = (float*)d_out;

  const int n  = in_sizes[0] / HID;   // 100000
  const int nE = in_sizes[2];         // 1000000
  const int* src = ei;
  const int* dst = ei + nE;

  const int B = (n + NPB - 1) / NPB;  // 391 buckets
  const int G1  = (nE + DFT * 4 - 1) / (DFT * 4);     // 489 blocks
  const int ept = (nE + G1 * DFT - 1) / (G1 * DFT);   // 4

  // ---- workspace layout (~23.2 MB) ----
  auto align512 = [](size_t v) { return (v + 511) & ~(size_t)511; };
  char* ws = (char*)d_ws;
  size_t off = 0;
  float* dinv        = (float*)(ws + off); off += align512((size_t)n * 4);
  int*   rowStart    = (int*)  (ws + off); off += align512((size_t)(n + 1) * 4);
  unsigned int* bucketCnt = (unsigned int*)(ws + off); off += align512((size_t)B * 16 * 4);
  int2*  edges       = (int2*) (ws + off); off += align512((size_t)B * CAP * 8 + 64);
  unsigned short* P2 = (unsigned short*)(ws + off); off += align512((size_t)n * HID * 2);
  // P1 (12.8 MB bf16) lives in d_out's first half: dead before k_agg8f
  // (the only writer of d_out) runs.
  unsigned short* P1 = (unsigned short*)d_out;

  const int aggBlocks = (n + 31) / 32;  // 32 nodes per block (4 waves x 8)

  // ---- 5 dispatches total ----
  hipMemsetAsync(bucketCnt, 0, (size_t)B * 16 * 4, stream);
  k_bucket1<<<G1, DFT, 0, stream>>>(src, dst, ew, bucketCnt, edges, B, ept, nE);
  k_degfillG<<<B, DFT, 0, stream>>>(edges, bucketCnt, x, W1, dinv, rowStart, P1, n);

  // layer-1 aggregate fused with layer-2 projection (P1 -> P2)
  k_aggG<<<aggBlocks, 256, 0, stream>>>(edges, rowStart, dinv,
                                        (const uint4*)P1, b1, W2, P2, n);

  // layer-2 aggregate -> final output
  k_agg8f<<<aggBlocks, 256, 0, stream>>>(edges, rowStart, dinv,
                                         (const uint4*)P2, b2, out, n);
}

// Round 6
// 181.085 us; speedup vs baseline: 1.1637x; 1.0071x over previous
//
#include <hip/hip_runtime.h>

#define HID 64
#define NPB 256    // nodes per bucket (bucket = dst >> 8)
#define CAP 3072   // fixed per-bucket edge capacity: mean 2560, sd ~50 -> ~10 sigma margin
#define DFT 512    // degfill/bucket1 block size (8 waves)
#define RCAP 6     // register-cache records per thread; RCAP*DFT=3072 >= CAP-8 covers whole bucket

typedef __attribute__((ext_vector_type(8))) short bf16x8;
typedef __attribute__((ext_vector_type(4))) float f32x4;

__device__ inline float bf2f(unsigned short u) {
  return __uint_as_float((unsigned int)u << 16);
}
__device__ inline unsigned short f2bf(float f) {
  unsigned int u = __float_as_uint(f);
  u += 0x7fff + ((u >> 16) & 1);  // round-to-nearest-even
  return (unsigned short)(u >> 16);
}
__device__ inline float bfLo(unsigned int u) { return __uint_as_float(u << 16); }
__device__ inline float bfHi(unsigned int u) { return __uint_as_float(u & 0xffff0000u); }

// ---- S1 FUSED (hist+reserve+scatter): LDS hist -> one global atomicAdd per
// bucket per block (reserve) -> scatter into fixed-capacity bucket regions.
// Bucket c occupies edges[c*CAP .. c*CAP+cnt_c). ----
__global__ __launch_bounds__(DFT) void k_bucket1(const int* __restrict__ src,
                                                 const int* __restrict__ dst,
                                                 const float* __restrict__ ew,
                                                 unsigned int* __restrict__ bucketCnt,  // B*16 padded
                                                 int2* __restrict__ edges,
                                                 int B, int ept, int nE) {
  __shared__ unsigned int hist[512];
  hist[threadIdx.x] = 0;
  __syncthreads();
  int base = blockIdx.x * DFT * ept;
  for (int i = 0; i < ept; ++i) {
    int e = base + i * DFT + threadIdx.x;
    if (e < nE) atomicAdd(&hist[(unsigned)dst[e] >> 8], 1u);
  }
  __syncthreads();
  for (int c = threadIdx.x; c < B; c += DFT) {
    unsigned int h = hist[c];
    unsigned int b = 0;
    if (h) b = atomicAdd(&bucketCnt[c * 16], h);  // 64B-padded line per bucket
    hist[c] = (unsigned)(c * CAP) + b;            // absolute write cursor
  }
  __syncthreads();
  for (int i = 0; i < ept; ++i) {
    int e = base + i * DFT + threadIdx.x;
    if (e < nE) {
      int d = dst[e];
      int c = (unsigned)d >> 8;
      int slot = (int)atomicAdd(&hist[c], 1u);
      if (slot < (c + 1) * CAP)  // never taken statistically; memory safety only
        edges[slot] = make_int2(src[e] | ((d & 255) << 24), __float_as_int(ew[e]));
    }
  }
}

// ---- S2 FUSED (degfill + gemm1): phase A = deg + count + scan + IN-PLACE
// row-sorted rewrite (register-cached, all reads before any write); phase B =
// MFMA gemm over this bucket's 256 rows with dinv in LDS. Out = P1 lives in
// d_out's first half (dead before the final aggregate overwrites d_out).
// rowStart[g+1] = END offset of row g; starts are c*CAP arithmetically.
// 8 zero-sentinel edges pad each bucket for the aggregator's 8-wide tail reads. ----
__global__ __launch_bounds__(DFT) void k_degfillG(int2* __restrict__ edges,
                                                  const unsigned int* __restrict__ bucketCnt,
                                                  const float* __restrict__ X,
                                                  const float* __restrict__ W,
                                                  float* __restrict__ dinv,
                                                  int* __restrict__ rowStart,
                                                  unsigned short* __restrict__ Out, int n) {
  __shared__ float deg[NPB];
  __shared__ int cnt[NPB];
  __shared__ int s[NPB];
  if (threadIdx.x < NPB) {
    deg[threadIdx.x] = 1.0f;  // self-loop weight
    cnt[threadIdx.x] = 0;
  }
  __syncthreads();
  int c = blockIdx.x;
  int i0 = c * CAP;
  int bc = (int)bucketCnt[c * 16];
  if (bc > CAP - 8) bc = CAP - 8;  // never taken; memory safety
  int i1 = i0 + bc;
  int2 rec[RCAP];
  int myCnt = 0;
  for (int i = i0 + threadIdx.x; i < i1; i += DFT) {
    int2 r = edges[i];
#pragma unroll
    for (int k = 0; k < RCAP; ++k)
      if (k == myCnt) rec[k] = r;
    myCnt++;
    int l = (unsigned)r.x >> 24;
    atomicAdd(&deg[l], __int_as_float(r.y));
    atomicAdd(&cnt[l], 1);
  }
  __syncthreads();  // ALL reads of edges[] done before any write below
  int v = 0;
  if (threadIdx.x < NPB) {
    v = cnt[threadIdx.x];
    s[threadIdx.x] = v;
  }
  __syncthreads();
  for (int o = 1; o < NPB; o <<= 1) {
    int t = (threadIdx.x < NPB && threadIdx.x >= (unsigned)o) ? s[threadIdx.x - o] : 0;
    __syncthreads();
    if (threadIdx.x < NPB) s[threadIdx.x] += t;
    __syncthreads();
  }
  if (threadIdx.x < NPB) {
    int rowBase = i0 + s[threadIdx.x] - v;
    float di = rsqrtf(deg[threadIdx.x]);
    int g = c * NPB + threadIdx.x;
    if (g < n) {
      rowStart[g + 1] = i0 + s[threadIdx.x];  // inclusive end of row g
      dinv[g] = di;
    }
    cnt[threadIdx.x] = rowBase;  // reuse as cursor (deg reused as ddst below)
  }
  if (threadIdx.x < 8) edges[i1 + threadIdx.x] = make_int2(0, 0);  // zero sentinels
  __syncthreads();
  if (threadIdx.x < NPB) deg[threadIdx.x] = rsqrtf(deg[threadIdx.x]);  // ddst = di
  __syncthreads();
#pragma unroll
  for (int k = 0; k < RCAP; ++k) {
    if (k < myCnt) {
      int2 r = rec[k];
      int l = (unsigned)r.x >> 24;
      int pos = atomicAdd(&cnt[l], 1);
      float norm = __int_as_float(r.y) * deg[l];  // ew * dinv[dst]
      edges[pos] = make_int2(r.x & 0xFFFFFF, __float_as_int(norm));
    }
  }
  // ---- phase B: gemm1 for rows [c*256, c*256+256). deg[] holds di. ----
  __syncthreads();
  int wv = threadIdx.x >> 6;
  int lane = threadIdx.x & 63;
  int m16 = lane & 15;
  int q = lane >> 4;
  bf16x8 Bb[4][2], Br[4][2];
#pragma unroll
  for (int nt = 0; nt < 4; ++nt)
#pragma unroll
    for (int kh = 0; kh < 2; ++kh) {
      int ncol = nt * 16 + m16;
      int k0 = kh * 32 + q * 8;
#pragma unroll
      for (int j = 0; j < 8; ++j) {
        float w = W[(k0 + j) * HID + ncol];
        unsigned short wb = f2bf(w);
        Bb[nt][kh][j] = (short)wb;
        Br[nt][kh][j] = (short)f2bf(w - bf2f(wb));
      }
    }
#pragma unroll
  for (int sub = 0; sub < 2; ++sub) {
    int slice = sub * 8 + wv;  // 16 slices of 16 rows over 8 waves x 2 iters
    int rowBase2 = c * 256 + slice * 16;
    if (rowBase2 >= n) continue;
    int mc = rowBase2 + m16;
    if (mc >= n) mc = n - 1;
    bf16x8 A[2];
    const float* Xp = X + (size_t)mc * HID;
#pragma unroll
    for (int kh = 0; kh < 2; ++kh) {
      f32x4 x0 = *(const f32x4*)(Xp + kh * 32 + q * 8);
      f32x4 x1 = *(const f32x4*)(Xp + kh * 32 + q * 8 + 4);
#pragma unroll
      for (int j = 0; j < 4; ++j) {
        A[kh][j] = (short)f2bf(x0[j]);
        A[kh][4 + j] = (short)f2bf(x1[j]);
      }
    }
    float dv = deg[slice * 16 + m16];  // di for row rowBase2+m16 (LDS)
#pragma unroll
    for (int nt = 0; nt < 4; ++nt) {
      f32x4 acc = {0.f, 0.f, 0.f, 0.f};
      // swapped operands -> D transposed: lane holds row rowBase2+m16,
      // cols nt*16 + q*4 + r  => one contiguous 8B bf16x4 store per nt
      acc = __builtin_amdgcn_mfma_f32_16x16x32_bf16(Bb[nt][0], A[0], acc, 0, 0, 0);
      acc = __builtin_amdgcn_mfma_f32_16x16x32_bf16(Bb[nt][1], A[1], acc, 0, 0, 0);
      acc = __builtin_amdgcn_mfma_f32_16x16x32_bf16(Br[nt][0], A[0], acc, 0, 0, 0);
      acc = __builtin_amdgcn_mfma_f32_16x16x32_bf16(Br[nt][1], A[1], acc, 0, 0, 0);
      if (rowBase2 + m16 < n) {
        ushort4 o;
        o.x = f2bf(acc[0] * dv);
        o.y = f2bf(acc[1] * dv);
        o.z = f2bf(acc[2] * dv);
        o.w = f2bf(acc[3] * dv);
        *(ushort4*)(&Out[(size_t)(rowBase2 + m16) * HID + nt * 16 + q * 4]) = o;
      }
    }
  }
}

// 8-wide edge step: 4 independent int4 edge loads + 8 independent H-row
// gathers per iteration (2x the MLP of the 4-wide version; same padded slot
// count at E[max-of-8 deg] ~ 15.5). Accumulation order per channel unchanged.
#define AGG_STEP8(EDG, H8P, QL, E0, E1, B2)                                   \
  int4 p0 = *(const int4*)((EDG) + (B2));                                     \
  int4 p1 = *(const int4*)((EDG) + (B2) + 2);                                 \
  int4 p2 = *(const int4*)((EDG) + (B2) + 4);                                 \
  int4 p3 = *(const int4*)((EDG) + (B2) + 6);                                 \
  uint4 h0 = (H8P)[(size_t)(unsigned)p0.x * 8u + (QL)];                       \
  uint4 h1 = (H8P)[(size_t)(unsigned)p0.z * 8u + (QL)];                       \
  uint4 h2 = (H8P)[(size_t)(unsigned)p1.x * 8u + (QL)];                       \
  uint4 h3 = (H8P)[(size_t)(unsigned)p1.z * 8u + (QL)];                       \
  uint4 h4 = (H8P)[(size_t)(unsigned)p2.x * 8u + (QL)];                       \
  uint4 h5 = (H8P)[(size_t)(unsigned)p2.z * 8u + (QL)];                       \
  uint4 h6 = (H8P)[(size_t)(unsigned)p3.x * 8u + (QL)];                       \
  uint4 h7 = (H8P)[(size_t)(unsigned)p3.z * 8u + (QL)];                       \
  float n0 = ((B2) >= (E0)) ? __int_as_float(p0.y) : 0.f;                     \
  float n1 = ((B2) + 1 < (E1)) ? __int_as_float(p0.w) : 0.f;                  \
  float n2 = ((B2) + 2 < (E1)) ? __int_as_float(p1.y) : 0.f;                  \
  float n3 = ((B2) + 3 < (E1)) ? __int_as_float(p1.w) : 0.f;                  \
  float n4 = ((B2) + 4 < (E1)) ? __int_as_float(p2.y) : 0.f;                  \
  float n5 = ((B2) + 5 < (E1)) ? __int_as_float(p2.w) : 0.f;                  \
  float n6 = ((B2) + 6 < (E1)) ? __int_as_float(p3.y) : 0.f;                  \
  float n7 = ((B2) + 7 < (E1)) ? __int_as_float(p3.w) : 0.f;                  \
  a0 = fmaf(n0, bfLo(h0.x), a0); a1 = fmaf(n0, bfHi(h0.x), a1);               \
  a2 = fmaf(n0, bfLo(h0.y), a2); a3 = fmaf(n0, bfHi(h0.y), a3);               \
  a4 = fmaf(n0, bfLo(h0.z), a4); a5 = fmaf(n0, bfHi(h0.z), a5);               \
  a6 = fmaf(n0, bfLo(h0.w), a6); a7 = fmaf(n0, bfHi(h0.w), a7);               \
  a0 = fmaf(n1, bfLo(h1.x), a0); a1 = fmaf(n1, bfHi(h1.x), a1);               \
  a2 = fmaf(n1, bfLo(h1.y), a2); a3 = fmaf(n1, bfHi(h1.y), a3);               \
  a4 = fmaf(n1, bfLo(h1.z), a4); a5 = fmaf(n1, bfHi(h1.z), a5);               \
  a6 = fmaf(n1, bfLo(h1.w), a6); a7 = fmaf(n1, bfHi(h1.w), a7);               \
  a0 = fmaf(n2, bfLo(h2.x), a0); a1 = fmaf(n2, bfHi(h2.x), a1);               \
  a2 = fmaf(n2, bfLo(h2.y), a2); a3 = fmaf(n2, bfHi(h2.y), a3);               \
  a4 = fmaf(n2, bfLo(h2.z), a4); a5 = fmaf(n2, bfHi(h2.z), a5);               \
  a6 = fmaf(n2, bfLo(h2.w), a6); a7 = fmaf(n2, bfHi(h2.w), a7);               \
  a0 = fmaf(n3, bfLo(h3.x), a0); a1 = fmaf(n3, bfHi(h3.x), a1);               \
  a2 = fmaf(n3, bfLo(h3.y), a2); a3 = fmaf(n3, bfHi(h3.y), a3);               \
  a4 = fmaf(n3, bfLo(h3.z), a4); a5 = fmaf(n3, bfHi(h3.z), a5);               \
  a6 = fmaf(n3, bfLo(h3.w), a6); a7 = fmaf(n3, bfHi(h3.w), a7);               \
  a0 = fmaf(n4, bfLo(h4.x), a0); a1 = fmaf(n4, bfHi(h4.x), a1);               \
  a2 = fmaf(n4, bfLo(h4.y), a2); a3 = fmaf(n4, bfHi(h4.y), a3);               \
  a4 = fmaf(n4, bfLo(h4.z), a4); a5 = fmaf(n4, bfHi(h4.z), a5);               \
  a6 = fmaf(n4, bfLo(h4.w), a6); a7 = fmaf(n4, bfHi(h4.w), a7);               \
  a0 = fmaf(n5, bfLo(h5.x), a0); a1 = fmaf(n5, bfHi(h5.x), a1);               \
  a2 = fmaf(n5, bfLo(h5.y), a2); a3 = fmaf(n5, bfHi(h5.y), a3);               \
  a4 = fmaf(n5, bfLo(h5.z), a4); a5 = fmaf(n5, bfHi(h5.z), a5);               \
  a6 = fmaf(n5, bfLo(h5.w), a6); a7 = fmaf(n5, bfHi(h5.w), a7);               \
  a0 = fmaf(n6, bfLo(h6.x), a0); a1 = fmaf(n6, bfHi(h6.x), a1);               \
  a2 = fmaf(n6, bfLo(h6.y), a2); a3 = fmaf(n6, bfHi(h6.y), a3);               \
  a4 = fmaf(n6, bfLo(h6.z), a4); a5 = fmaf(n6, bfHi(h6.z), a5);               \
  a6 = fmaf(n6, bfLo(h6.w), a6); a7 = fmaf(n6, bfHi(h6.w), a7);               \
  a0 = fmaf(n7, bfLo(h7.x), a0); a1 = fmaf(n7, bfHi(h7.x), a1);               \
  a2 = fmaf(n7, bfLo(h7.y), a2); a3 = fmaf(n7, bfHi(h7.y), a3);               \
  a4 = fmaf(n7, bfLo(h7.z), a4); a5 = fmaf(n7, bfHi(h7.z), a5);               \
  a6 = fmaf(n7, bfLo(h7.w), a6); a7 = fmaf(n7, bfHi(h7.w), a7);

// ---- FUSED layer-1 aggregate + layer-2 projection: each block owns 32 nodes
// (4 waves x 8). Wave computes ReLU(agg+b1) rows -> 5KB LDS -> each wave runs
// one 16-col n-tile of the 32-row MFMA gemm (W2 frags, transposed-D stores).
// Writes P2 = bf16(dinv*(h1@W2)) to workspace; never touches d_out (P1 src). ----
__global__ __launch_bounds__(256) void k_aggG(const int2* __restrict__ edges,
                                              const int* __restrict__ rowStart,
                                              const float* __restrict__ dinv,
                                              const uint4* __restrict__ H8,  // P1: 8 x uint4 per node
                                              const float* __restrict__ bias,
                                              const float* __restrict__ W,   // W2
                                              unsigned short* __restrict__ Out,  // P2
                                              int n) {
  __shared__ uint4 sh[32][10];  // [row][uint4 col], padded 8->10
  __shared__ float sdi[32];
  int wv = threadIdx.x >> 6;
  int lane = threadIdx.x & 63;
  int q = lane >> 3;    // which of 8 nodes in this wave
  int ql = lane & 7;    // channels 8*ql .. 8*ql+7
  int base = blockIdx.x * 32;
  int node = base + wv * 8 + q;
  if (node < n) {
    int e0 = rowStart[node];
    if ((node & 255) == 0) e0 = (node >> 8) * CAP;  // bucket start (rowStart[g] holds ends)
    int e1 = rowStart[node + 1];
    float di = dinv[node];
    uint4 su = H8[(size_t)node * 8 + ql];
    float a0 = di * bfLo(su.x), a1 = di * bfHi(su.x);
    float a2 = di * bfLo(su.y), a3 = di * bfHi(su.y);
    float a4 = di * bfLo(su.z), a5 = di * bfHi(su.z);
    float a6 = di * bfLo(su.w), a7 = di * bfHi(su.w);
    for (int b2 = e0 & ~1; b2 < e1; b2 += 8) {
      AGG_STEP8(edges, H8, ql, e0, e1, b2)
    }
    float4 bv0 = ((const float4*)bias)[2 * ql];
    float4 bv1 = ((const float4*)bias)[2 * ql + 1];
    a0 = fmaxf(a0 + bv0.x, 0.f); a1 = fmaxf(a1 + bv0.y, 0.f);
    a2 = fmaxf(a2 + bv0.z, 0.f); a3 = fmaxf(a3 + bv0.w, 0.f);
    a4 = fmaxf(a4 + bv1.x, 0.f); a5 = fmaxf(a5 + bv1.y, 0.f);
    a6 = fmaxf(a6 + bv1.z, 0.f); a7 = fmaxf(a7 + bv1.w, 0.f);
    uint4 o;
    o.x = (unsigned)f2bf(a0) | ((unsigned)f2bf(a1) << 16);
    o.y = (unsigned)f2bf(a2) | ((unsigned)f2bf(a3) << 16);
    o.z = (unsigned)f2bf(a4) | ((unsigned)f2bf(a5) << 16);
    o.w = (unsigned)f2bf(a6) | ((unsigned)f2bf(a7) << 16);
    sh[wv * 8 + q][ql] = o;
    if (ql == 0) sdi[wv * 8 + q] = di;
  } else {
    sh[wv * 8 + q][ql] = make_uint4(0, 0, 0, 0);
    if (ql == 0) sdi[wv * 8 + q] = 0.f;
  }
  __syncthreads();
  // ---- gemm2 phase: 32 rows from LDS; this wave owns n-tile nt = wv ----
  int m16 = lane & 15;
  int qq = lane >> 4;
  bf16x8 Bb[2], Br[2];
#pragma unroll
  for (int kh = 0; kh < 2; ++kh) {
    int ncol = wv * 16 + m16;
    int k0 = kh * 32 + qq * 8;
#pragma unroll
    for (int j = 0; j < 8; ++j) {
      float w = W[(k0 + j) * HID + ncol];  // L1-hot (16 KB)
      unsigned short wb = f2bf(w);
      Bb[kh][j] = (short)wb;
      Br[kh][j] = (short)f2bf(w - bf2f(wb));
    }
  }
#pragma unroll
  for (int rt = 0; rt < 2; ++rt) {
    int row = rt * 16 + m16;
    bf16x8 A0 = *(const bf16x8*)&sh[row][qq];      // k = qq*8 .. +7
    bf16x8 A1 = *(const bf16x8*)&sh[row][4 + qq];  // k = 32 + qq*8 .. +7
    f32x4 acc = {0.f, 0.f, 0.f, 0.f};
    acc = __builtin_amdgcn_mfma_f32_16x16x32_bf16(Bb[0], A0, acc, 0, 0, 0);
    acc = __builtin_amdgcn_mfma_f32_16x16x32_bf16(Bb[1], A1, acc, 0, 0, 0);
    acc = __builtin_amdgcn_mfma_f32_16x16x32_bf16(Br[0], A0, acc, 0, 0, 0);
    acc = __builtin_amdgcn_mfma_f32_16x16x32_bf16(Br[1], A1, acc, 0, 0, 0);
    int gnode = base + row;
    if (gnode < n) {
      float dv = sdi[row];
      ushort4 o;
      o.x = f2bf(acc[0] * dv);
      o.y = f2bf(acc[1] * dv);
      o.z = f2bf(acc[2] * dv);
      o.w = f2bf(acc[3] * dv);
      *(ushort4*)(&Out[(size_t)gnode * HID + wv * 16 + qq * 4]) = o;
    }
  }
}

// ---- CSR aggregate (layer 2): 8 nodes per wave, float4 output + bias ----
__global__ __launch_bounds__(256) void k_agg8f(const int2* __restrict__ edges,
                                               const int* __restrict__ rowStart,
                                               const float* __restrict__ dinv,
                                               const uint4* __restrict__ H8,  // P2
                                               const float* __restrict__ bias,
                                               float* __restrict__ outp, int n) {
  int gwave = (blockIdx.x * 256 + threadIdx.x) >> 6;
  int lane = threadIdx.x & 63;
  int q = lane >> 3;
  int ql = lane & 7;
  int node = gwave * 8 + q;
  if (node >= n) return;
  int e0 = rowStart[node];
  if ((node & 255) == 0) e0 = (node >> 8) * CAP;
  int e1 = rowStart[node + 1];
  float di = dinv[node];
  uint4 su = H8[(size_t)node * 8 + ql];
  float a0 = di * bfLo(su.x), a1 = di * bfHi(su.x);
  float a2 = di * bfLo(su.y), a3 = di * bfHi(su.y);
  float a4 = di * bfLo(su.z), a5 = di * bfHi(su.z);
  float a6 = di * bfLo(su.w), a7 = di * bfHi(su.w);
  for (int b2 = e0 & ~1; b2 < e1; b2 += 8) {
    AGG_STEP8(edges, H8, ql, e0, e1, b2)
  }
  float4 bv0 = ((const float4*)bias)[2 * ql];
  float4 bv1 = ((const float4*)bias)[2 * ql + 1];
  float4 o0, o1;
  o0.x = a0 + bv0.x; o0.y = a1 + bv0.y; o0.z = a2 + bv0.z; o0.w = a3 + bv0.w;
  o1.x = a4 + bv1.x; o1.y = a5 + bv1.y; o1.z = a6 + bv1.z; o1.w = a7 + bv1.w;
  ((float4*)outp)[(size_t)node * 16 + 2 * ql] = o0;
  ((float4*)outp)[(size_t)node * 16 + 2 * ql + 1] = o1;
}

extern "C" void kernel_launch(void* const* d_in, const int* in_sizes, int n_in,
                              void* d_out, int out_size, void* d_ws, size_t ws_size,
                              hipStream_t stream) {
  const float* x  = (const float*)d_in[0];
  const int*   ei = (const int*)d_in[1];
  const float* ew = (const float*)d_in[2];
  const float* W1 = (const float*)d_in[3];
  const float* b1 = (const float*)d_in[4];
  const float* W2 = (const float*)d_in[5];
  const float* b2 = (const float*)d_in[6];
  float* out = (float*)d_out;

  const int n  = in_sizes[0] / HID;   // 100000
  const int nE = in_sizes[2];         // 1000000
  const int* src = ei;
  const int* dst = ei + nE;

  const int B = (n + NPB - 1) / NPB;  // 391 buckets
  const int G1  = (nE + DFT * 4 - 1) / (DFT * 4);     // 489 blocks
  const int ept = (nE + G1 * DFT - 1) / (G1 * DFT);   // 4

  // ---- workspace layout (~23.2 MB) ----
  auto align512 = [](size_t v) { return (v + 511) & ~(size_t)511; };
  char* ws = (char*)d_ws;
  size_t off = 0;
  float* dinv        = (float*)(ws + off); off += align512((size_t)n * 4);
  int*   rowStart    = (int*)  (ws + off); off += align512((size_t)(n + 1) * 4);
  unsigned int* bucketCnt = (unsigned int*)(ws + off); off += align512((size_t)B * 16 * 4);
  int2*  edges       = (int2*) (ws + off); off += align512((size_t)B * CAP * 8 + 128);
  unsigned short* P2 = (unsigned short*)(ws + off); off += align512((size_t)n * HID * 2);
  // P1 (12.8 MB bf16) lives in d_out's first half: dead before k_agg8f
  // (the only writer of d_out) runs.
  unsigned short* P1 = (unsigned short*)d_out;

  const int aggBlocks = (n + 31) / 32;  // 32 nodes per block (4 waves x 8)

  // ---- 5 dispatches total ----
  hipMemsetAsync(bucketCnt, 0, (size_t)B * 16 * 4, stream);
  k_bucket1<<<G1, DFT, 0, stream>>>(src, dst, ew, bucketCnt, edges, B, ept, nE);
  k_degfillG<<<B, DFT, 0, stream>>>(edges, bucketCnt, x, W1, dinv, rowStart, P1, n);

  // layer-1 aggregate fused with layer-2 projection (P1 -> P2)
  k_aggG<<<aggBlocks, 256, 0, stream>>>(edges, rowStart, dinv,
                                        (const uint4*)P1, b1, W2, P2, n);

  // layer-2 aggregate -> final output
  k_agg8f<<<aggBlocks, 256, 0, stream>>>(edges, rowStart, dinv,
                                         (const uint4*)P2, b2, out, n);
}